// Round 1
// 191.759 us; speedup vs baseline: 1.3124x; 1.3124x over previous
//
#include <hip/hip_runtime.h>

#define HH 128
#define WW 128
#define CC 64
#define BS 1024

typedef float f4 __attribute__((ext_vector_type(4)));

__device__ __forceinline__ f4 vload(const float* __restrict__ p) {
    return *reinterpret_cast<const f4*>(p);
}
__device__ __forceinline__ void vstore(float* p, f4 v) {
    *reinterpret_cast<f4*>(p) = v;
}
__device__ __forceinline__ f4 vrelu(f4 a) {
    f4 r;
    #pragma unroll
    for (int i = 0; i < 4; ++i) r[i] = fmaxf(a[i], 0.f);
    return r;
}
__device__ __forceinline__ f4 vrsqrt_eps(f4 a) {
    f4 r;
    #pragma unroll
    for (int i = 0; i < 4; ++i) r[i] = rsqrtf(a[i] + 1e-3f);
    return r;
}
__device__ __forceinline__ f4 vrcp(f4 a) {
    f4 r;
    #pragma unroll
    for (int i = 0; i < 4; ++i) r[i] = 1.0f / a[i];
    return r;
}

__global__ __launch_bounds__(BS) void diffusion_fused(
    const float* __restrict__ s0,
    const float* __restrict__ kg,  const float* __restrict__ kg1,
    const float* __restrict__ kDx, const float* __restrict__ kDy,
    const float* __restrict__ bng,  const float* __restrict__ bng1,
    const float* __restrict__ bnDx, const float* __restrict__ bnDy,
    const float* __restrict__ bn_out,
    float* __restrict__ out)
{
    __shared__ float Lg[WW * CC];   // 32 KB: g row; reused as h1 buffer after phase 1b
    __shared__ float Lh[WW * CC];   // 32 KB: h0(=f) row

    const int t  = threadIdx.x;
    const int cq = t & 15;          // channel quad: channels 4cq..4cq+3
    const int c4 = cq << 2;
    const int wp = t >> 4;          // 0..63 -> w pair (2wp, 2wp+1)
    const int w0 = wp << 1;
    const int l  = t & 63;
    // channel-roll shuffles stay inside each 16-lane cq group (wrap mod 64 channels)
    const int lm = (l & 48) | ((l + 15) & 15);
    const int lp = (l & 48) | ((l + 1)  & 15);

    // bijective XCD swizzle: 2048 blocks = 8 XCDs x 256 contiguous rows
    const int bid = blockIdx.x;
    const int bh  = ((bid & 7) << 8) | (bid >> 3);
    const int hrow = bh & (HH - 1);
    const long rowbase = (long)bh * (WW * CC);

    const float DTc = 0.2f;

    // ---- phase 1a: 3x3 depthwise conv (SAME, zero pad), all float4 ----
    f4 acc[4][2];
    #pragma unroll
    for (int q = 0; q < 4; ++q) {
        acc[q][0] = (f4)0.f;
        acc[q][1] = (f4)0.f;
    }
    f4 fin[2];
    fin[0] = (f4)0.f; fin[1] = (f4)0.f;

    const float* wptr[4] = { kg, kg1, kDx, kDy };

    #pragma unroll
    for (int dh = -1; dh <= 1; ++dh) {
        const int h2 = hrow + dh;
        if (h2 < 0 || h2 >= HH) continue;          // block-uniform branch
        const float* rp = s0 + rowbase + (long)dh * (WW * CC);
        f4 in[4];                                  // columns w0-1 .. w0+2
        #pragma unroll
        for (int j = 0; j < 4; ++j) {
            const int wc = w0 - 1 + j;
            if (wc >= 0 && wc < WW) in[j] = vload(rp + wc * CC + c4);
            else                    in[j] = (f4)0.f;   // zero pad (conv only)
        }
        if (dh == 0) { fin[0] = in[1]; fin[1] = in[2]; }
        #pragma unroll
        for (int dw = 0; dw < 3; ++dw) {
            const int k = (dh + 1) * 3 + dw;
            #pragma unroll
            for (int q = 0; q < 4; ++q) {
                const f4 wq = vload(wptr[q] + k * CC + c4);
                acc[q][0] += in[dw]     * wq;      // point w0 uses cols w0-1..w0+1
                acc[q][1] += in[dw + 1] * wq;      // point w0+1 uses cols w0..w0+2
            }
        }
    }

    // ---- BN folds (y = s*x + b), per channel quad ----
    f4 s_g, b_g, s_g1, b_g1, s_dx, b_dx, s_dy, b_dy;
    #define BNFOLD(P, S, B) { \
        const f4 ga = vload((P) + c4);        \
        const f4 be = vload((P) + 64 + c4);   \
        const f4 mu = vload((P) + 128 + c4);  \
        const f4 va = vload((P) + 192 + c4);  \
        S = ga * vrsqrt_eps(va);              \
        B = be - mu * S; }
    BNFOLD(bng,  s_g,  b_g);
    BNFOLD(bng1, s_g1, b_g1);
    BNFOLD(bnDx, s_dx, b_dx);
    BNFOLD(bnDy, s_dy, b_dy);

    f4 gq[2], g1q[2];
    f4 cWm[2], cWp[2], cCm[2], cCp[2], A0[2], Pq[2], vy[2], hq[2];

    #pragma unroll
    for (int wi = 0; wi < 2; ++wi) {
        gq[wi]  = vrelu(acc[0][wi] * s_g  + b_g );
        g1q[wi] = vrelu(acc[1][wi] * s_g1 + b_g1);
        const f4 bx = vrelu(acc[2][wi] * s_dx + b_dx) * DTc;   // Bx = Dx*dt
        const f4 by = vrelu(acc[3][wi] * s_dy + b_dy) * DTc;   // By = Dy*dt

        // vy = 0.5*(g1[c-1] - g1[c+1]) wrap: in-quad + 2 shuffles
        const f4 g1v = g1q[wi];
        const float cm3 = __shfl(g1v.w, lm);
        const float cp0 = __shfl(g1v.x, lp);
        f4 cm, cp;
        cm.x = cm3;   cm.y = g1v.x; cm.z = g1v.y; cm.w = g1v.z;
        cp.x = g1v.y; cp.y = g1v.z; cp.z = g1v.w; cp.w = cp0;
        vy[wi] = 0.5f * (cm - cp);

        const f4 Dv = vrcp((f4)1.f + 2.f * bx + 2.f * by);
        const f4 Ax = gq[wi]  * DTc;
        const f4 Ay = g1q[wi] * DTc;
        cWm[wi] = Dv * (2.f * bx - Ax);    // coeff of h[w-1]
        cWp[wi] = Dv * (2.f * bx + Ax);    // coeff of h[w+1]
        cCm[wi] = Dv * (2.f * by - Ay);    // coeff of h[c-1]
        cCp[wi] = Dv * (2.f * by + Ay);    // coeff of h[c+1]
        // h0 == f in BOTH iterations (K=2, h0 lags by one step)
        A0[wi]  = Dv * fin[wi] * ((f4)(1.f + 2.f * DTc) - 2.f * bx - 2.f * by);
        Pq[wi]  = Dv * (-2.f * DTc);       // cE = Pq*(ux+vy)
        hq[wi]  = fin[wi];

        const int w = w0 + wi;
        vstore(&Lg[w * CC + c4], gq[wi]);
        vstore(&Lh[w * CC + c4], fin[wi]);
    }
    __syncthreads();   // barrier A: g,f visible

    // ---- phase 1b: cE from ux (W-neighbors of g wrap via LDS) ----
    f4 cE[2];
    #pragma unroll
    for (int wi = 0; wi < 2; ++wi) {
        const int w = w0 + wi;
        const f4 gm = vload(&Lg[((w - 1) & (WW - 1)) * CC + c4]);
        const f4 gp = vload(&Lg[((w + 1) & (WW - 1)) * CC + c4]);
        cE[wi] = Pq[wi] * ((f4)0.5f * (gm - gp) + vy[wi]);
    }

    // ---- PDE iter 1 (h = f, neighbors from Lh) ----
    f4 hn[2];
    #pragma unroll
    for (int wi = 0; wi < 2; ++wi) {
        const int w = w0 + wi;
        const f4 hm = vload(&Lh[((w - 1) & (WW - 1)) * CC + c4]);
        const f4 hp = vload(&Lh[((w + 1) & (WW - 1)) * CC + c4]);
        const f4 hv = hq[wi];
        const float m3 = __shfl(hv.w, lm);
        const float p0 = __shfl(hv.x, lp);
        f4 cm, cp;
        cm.x = m3;   cm.y = hv.x; cm.z = hv.y; cm.w = hv.z;
        cp.x = hv.y; cp.y = hv.z; cp.z = hv.w; cp.w = p0;
        hn[wi] = A0[wi] + cE[wi] * hv + cWm[wi] * hm + cWp[wi] * hp
               + cCm[wi] * cm + cCp[wi] * cp;
    }
    __syncthreads();   // barrier B: all Lg(1b)/Lh(iter1) reads done
    #pragma unroll
    for (int wi = 0; wi < 2; ++wi) {
        vstore(&Lg[(w0 + wi) * CC + c4], hn[wi]);   // Lg now holds h1
        hq[wi] = hn[wi];
    }
    __syncthreads();   // barrier C: h1 visible

    // ---- PDE iter 2 (neighbors from Lg = h1) ----
    #pragma unroll
    for (int wi = 0; wi < 2; ++wi) {
        const int w = w0 + wi;
        const f4 hm = vload(&Lg[((w - 1) & (WW - 1)) * CC + c4]);
        const f4 hp = vload(&Lg[((w + 1) & (WW - 1)) * CC + c4]);
        const f4 hv = hq[wi];
        const float m3 = __shfl(hv.w, lm);
        const float p0 = __shfl(hv.x, lp);
        f4 cm, cp;
        cm.x = m3;   cm.y = hv.x; cm.z = hv.y; cm.w = hv.z;
        cp.x = hv.y; cp.y = hv.z; cp.z = hv.w; cp.w = p0;
        hn[wi] = A0[wi] + cE[wi] * hv + cWm[wi] * hm + cWp[wi] * hp
               + cCm[wi] * cm + cCp[wi] * cp;
    }

    // ---- epilogue: BN + ReLU, float4 store ----
    f4 s_o, b_o;
    BNFOLD(bn_out, s_o, b_o);
    #undef BNFOLD
    #pragma unroll
    for (int wi = 0; wi < 2; ++wi) {
        vstore(out + rowbase + (long)(w0 + wi) * CC + c4,
               vrelu(hn[wi] * s_o + b_o));
    }
}

extern "C" void kernel_launch(void* const* d_in, const int* in_sizes, int n_in,
                              void* d_out, int out_size, void* d_ws, size_t ws_size,
                              hipStream_t stream) {
    const float* s0   = (const float*)d_in[0];
    const float* kg   = (const float*)d_in[1];
    const float* kg1  = (const float*)d_in[2];
    const float* kDx  = (const float*)d_in[3];
    const float* kDy  = (const float*)d_in[4];
    const float* bng  = (const float*)d_in[5];
    const float* bng1 = (const float*)d_in[6];
    const float* bnDx = (const float*)d_in[7];
    const float* bnDy = (const float*)d_in[8];
    const float* bno  = (const float*)d_in[9];
    float* out = (float*)d_out;

    dim3 grid(16 * 128);   // one block per (batch, row), XCD-swizzled in-kernel
    dim3 block(BS);
    diffusion_fused<<<grid, block, 0, stream>>>(
        s0, kg, kg1, kDx, kDy, bng, bng1, bnDx, bnDy, bno, out);
}